// Round 1
// baseline (293.119 us; speedup 1.0000x reference)
//
#include <hip/hip_runtime.h>
#include <cstdint>

// Problem constants: B=2, L=2048, D=1024, H=16, DK=64
#define SEQ     2048
#define DMODEL  1024
#define NHEAD   16
#define DKH     64
#define NTOK    4096      // B*L
#define LDQKV   3072      // qkv buffer row stride (q|k|v)

typedef __bf16 bf16x8 __attribute__((ext_vector_type(8)));
typedef __bf16 bf16x4 __attribute__((ext_vector_type(4)));
typedef float  f32x4  __attribute__((ext_vector_type(4)));

#define MFMA_BF16(a, b, c) __builtin_amdgcn_mfma_f32_16x16x32_bf16((a), (b), (c), 0, 0, 0)

// async global->LDS copy, 16B per lane; LDS dest is wave-uniform base + lane*16
__device__ inline void async_copy16(const void* g, void* l) {
  __builtin_amdgcn_global_load_lds(
      reinterpret_cast<const __attribute__((address_space(1))) void*>(
          reinterpret_cast<uintptr_t>(g)),
      reinterpret_cast<__attribute__((address_space(3))) void*>(
          reinterpret_cast<uintptr_t>(l)),
      16, 0, 0);
}

__device__ inline bf16x4 cvt4(float4 v) {
  bf16x4 r;
  r[0] = (__bf16)v.x; r[1] = (__bf16)v.y; r[2] = (__bf16)v.z; r[3] = (__bf16)v.w;
  return r;
}

// ---------------- pack: fp32 -> bf16 casts + weight/bias concat ----------------
__global__ __launch_bounds__(256) void pack_kernel(
    const float4* __restrict__ x,
    const float4* __restrict__ wq, const float4* __restrict__ wk,
    const float4* __restrict__ wv, const float4* __restrict__ wo,
    const float4* __restrict__ bq, const float4* __restrict__ bk,
    const float4* __restrict__ bv,
    bf16x4* __restrict__ xb, bf16x4* __restrict__ wqkv,
    bf16x4* __restrict__ wob, float4* __restrict__ bcat)
{
  const int NX = NTOK * DMODEL / 4;       // 1048576 float4 groups of x
  const int NW = DMODEL * DMODEL / 4;     // 262144 per weight
  const int TOT = NX + 4 * NW + 3 * (DMODEL / 4);
  for (int g = blockIdx.x * 256 + threadIdx.x; g < TOT; g += gridDim.x * 256) {
    if (g < NX) {
      xb[g] = cvt4(x[g]);
    } else if (g < NX + 3 * NW) {
      int g2 = g - NX;
      const float4* s = (g2 < NW) ? wq : (g2 < 2 * NW ? wk : wv);
      wqkv[g2] = cvt4(s[g2 & (NW - 1)]);
    } else if (g < NX + 4 * NW) {
      int g3 = g - NX - 3 * NW;
      wob[g3] = cvt4(wo[g3]);
    } else {
      int g4 = g - NX - 4 * NW;
      const float4* s = (g4 < 256) ? bq : (g4 < 512 ? bk : bv);
      bcat[g4] = s[g4 & 255];
    }
  }
}

// ---------------- GEMM: C[M,N] = A[M,K] * W[N,K]^T + bias, K=1024 -------------
// m97-style: 128x128 block tile, 4 waves each 64x64 (4x4 of 16x16x32 MFMA),
// BK=32 staged via global_load_lds (LDS layout [row][32] bf16, no pad: row
// stride = 64B = 16 banks -> b128 fragment reads are effectively conflict-free).
__global__ __launch_bounds__(256) void gemm128_bias(
    const __bf16* __restrict__ A, const __bf16* __restrict__ W,
    const float* __restrict__ bias, void* __restrict__ C,
    int ldc, int out_bf16)
{
  constexpr int K = 1024;
  __shared__ __bf16 sA[128 * 32];
  __shared__ __bf16 sB[128 * 32];
  const int tid  = threadIdx.x;
  const int wave = tid >> 6, lane = tid & 63;
  const int quad = lane >> 4, l16 = lane & 15;
  const size_t m0 = (size_t)blockIdx.x * 128;
  const size_t n0 = (size_t)blockIdx.y * 128;
  const int wm = (wave & 1) * 64, wn = (wave >> 1) * 64;

  // staging: 8 groups of 16 rows; wave w does groups 2w, 2w+1 for A and B
  const int g0 = wave * 2;
  const int sr = lane >> 2;          // row within 16-row group
  const int sc = (lane & 3) * 8;     // bf16 col offset within BK=32
  const __bf16* pa0 = A + (m0 + g0 * 16 + sr) * K + sc;
  const __bf16* pa1 = A + (m0 + g0 * 16 + 16 + sr) * K + sc;
  const __bf16* pb0 = W + (n0 + g0 * 16 + sr) * K + sc;
  const __bf16* pb1 = W + (n0 + g0 * 16 + 16 + sr) * K + sc;
  __bf16* la0 = sA + g0 * 512;
  __bf16* la1 = sA + g0 * 512 + 512;
  __bf16* lb0 = sB + g0 * 512;
  __bf16* lb1 = sB + g0 * 512 + 512;

  f32x4 acc[4][4];
  const f32x4 z = {0.f, 0.f, 0.f, 0.f};
#pragma unroll
  for (int i = 0; i < 4; ++i)
#pragma unroll
    for (int j = 0; j < 4; ++j) acc[i][j] = z;

  for (int k0 = 0; k0 < K; k0 += 32) {
    __syncthreads();                       // previous tile's reads done
    async_copy16(pa0 + k0, la0);
    async_copy16(pa1 + k0, la1);
    async_copy16(pb0 + k0, lb0);
    async_copy16(pb1 + k0, lb1);
    __syncthreads();                       // staging visible (vmcnt drained)

    bf16x8 af[4], bw[4];
#pragma unroll
    for (int i = 0; i < 4; ++i)
      af[i] = *(const bf16x8*)(sA + (wm + i * 16 + l16) * 32 + quad * 8);
#pragma unroll
    for (int j = 0; j < 4; ++j)
      bw[j] = *(const bf16x8*)(sB + (wn + j * 16 + l16) * 32 + quad * 8);
#pragma unroll
    for (int i = 0; i < 4; ++i)
#pragma unroll
      for (int j = 0; j < 4; ++j)
        acc[i][j] = MFMA_BF16(af[i], bw[j], acc[i][j]);
  }

  float bi[4];
#pragma unroll
  for (int j = 0; j < 4; ++j) bi[j] = bias[n0 + wn + j * 16 + l16];

#pragma unroll
  for (int i = 0; i < 4; ++i) {
#pragma unroll
    for (int j = 0; j < 4; ++j) {
#pragma unroll
      for (int r = 0; r < 4; ++r) {
        size_t row = m0 + wm + i * 16 + quad * 4 + r;
        size_t col = n0 + wn + j * 16 + l16;
        float v = acc[i][j][r] + bi[j];
        if (out_bf16) ((__bf16*)C)[row * ldc + col] = (__bf16)v;
        else          ((float*)C)[row * ldc + col] = v;
      }
    }
  }
}

// ---------------- V transpose: qkv v-slice (n, d) -> vt[(b,h,dk)][l] ----------
__global__ __launch_bounds__(256) void vtrans_kernel(
    const __bf16* __restrict__ qkv, __bf16* __restrict__ vt)
{
  __shared__ __bf16 t[64][66];   // +2 pad: transposed reads 2-way only
  const int tid = threadIdx.x;
  const int bh = blockIdx.x;           // b*16+h
  const int b = bh >> 4, h = bh & 15;
  const int l0 = blockIdx.y * 64;
  const int r4 = tid >> 6;             // 0..3
  const int c  = tid & 63;
#pragma unroll
  for (int rep = 0; rep < 16; ++rep) {
    int ll = rep * 4 + r4;
    t[ll][c] = qkv[(size_t)(b * SEQ + l0 + ll) * LDQKV + 2048 + h * DKH + c];
  }
  __syncthreads();
#pragma unroll
  for (int rep = 0; rep < 16; ++rep) {
    int dk = rep * 4 + r4;
    vt[(size_t)(bh * DKH + dk) * SEQ + l0 + c] = t[c][dk];
  }
}

// ---------------- MFMA flash attention (causal) -------------------------------
// One wave per 16-query tile; 32-key tiles; online softmax.
// Q/K frags: 8 contiguous bf16 along dk (global). V frags: 8 contiguous bf16
// along l from pre-transposed vt. P: C-layout -> LDS -> A-layout round trip.
__global__ __launch_bounds__(256) void attn_kernel(
    const __bf16* __restrict__ qkv,   // [4096][3072]
    const __bf16* __restrict__ vt,    // [32*64][2048]
    __bf16* __restrict__ attn)        // [4096][1024]
{
  __shared__ __bf16 pbuf[4][16 * 72]; // per-wave P buffer, row stride 72 bf16
  const int tid  = threadIdx.x;
  const int wave = tid >> 6, lane = tid & 63;
  const int quad = lane >> 4, l16 = lane & 15;
  const int bh = blockIdx.x, b = bh >> 4, h = bh & 15;
  const int q0 = blockIdx.y * 64 + wave * 16;   // wave's first query row
  const size_t tokbase = (size_t)b * SEQ;

  bf16x8 qf[2];
#pragma unroll
  for (int s = 0; s < 2; ++s)
    qf[s] = *(const bf16x8*)(qkv + (tokbase + q0 + l16) * LDQKV + h * DKH + s * 32 + quad * 8);

  f32x4 o[4];
  float m_i[4], l_i[4];
  const f32x4 z = {0.f, 0.f, 0.f, 0.f};
#pragma unroll
  for (int t = 0; t < 4; ++t) o[t] = z;
#pragma unroll
  for (int r = 0; r < 4; ++r) { m_i[r] = -3.0e38f; l_i[r] = 0.f; }

  __bf16* pb = &pbuf[wave][0];
  const int ntiles = (q0 + 47) >> 5;   // max key0 <= q0, so every tile has valid keys

  for (int t0 = 0; t0 < ntiles; ++t0) {
    const int key0 = t0 * 32;

    bf16x8 kf[2][2], vf[4];
#pragma unroll
    for (int c = 0; c < 2; ++c)
#pragma unroll
      for (int s = 0; s < 2; ++s)
        kf[c][s] = *(const bf16x8*)(qkv + (tokbase + key0 + c * 16 + l16) * LDQKV
                                    + 1024 + h * DKH + s * 32 + quad * 8);
#pragma unroll
    for (int t = 0; t < 4; ++t)
      vf[t] = *(const bf16x8*)(vt + ((size_t)bh * DKH + t * 16 + l16) * SEQ + key0 + quad * 8);

    // S = Q K^T  (two 16-key column halves)
    f32x4 s0 = MFMA_BF16(qf[0], kf[0][0], z);
    s0 = MFMA_BF16(qf[1], kf[0][1], s0);
    f32x4 s1 = MFMA_BF16(qf[0], kf[1][0], z);
    s1 = MFMA_BF16(qf[1], kf[1][1], s1);

    float p0[4], p1[4], alpha[4];
#pragma unroll
    for (int r = 0; r < 4; ++r) {
      const int gq = q0 + quad * 4 + r;
      float a = (key0 + l16      <= gq) ? s0[r] * 0.125f : -3.0e38f;
      float c = (key0 + 16 + l16 <= gq) ? s1[r] * 0.125f : -3.0e38f;
      float mx = fmaxf(a, c);
      mx = fmaxf(mx, __shfl_xor(mx, 1));
      mx = fmaxf(mx, __shfl_xor(mx, 2));
      mx = fmaxf(mx, __shfl_xor(mx, 4));
      mx = fmaxf(mx, __shfl_xor(mx, 8));
      const float mn = fmaxf(m_i[r], mx);
      alpha[r] = __expf(m_i[r] - mn);
      m_i[r] = mn;
      p0[r] = __expf(a - mn);
      p1[r] = __expf(c - mn);
      float sm = p0[r] + p1[r];
      sm += __shfl_xor(sm, 1);
      sm += __shfl_xor(sm, 2);
      sm += __shfl_xor(sm, 4);
      sm += __shfl_xor(sm, 8);
      l_i[r] = l_i[r] * alpha[r] + sm;
    }

    // rescale O by alpha (per query row)
#pragma unroll
    for (int t = 0; t < 4; ++t)
#pragma unroll
      for (int r = 0; r < 4; ++r) o[t][r] *= alpha[r];

    // P: C-layout -> LDS (16 rows x 32 cols)
#pragma unroll
    for (int r = 0; r < 4; ++r) {
      const int row = quad * 4 + r;
      pb[row * 72 + l16]      = (__bf16)p0[r];
      pb[row * 72 + 16 + l16] = (__bf16)p1[r];
    }
    // A-layout fragment of P (row = l16, k = quad*8+j), 16B aligned
    bf16x8 ap = *(const bf16x8*)(pb + l16 * 72 + quad * 8);

#pragma unroll
    for (int t = 0; t < 4; ++t) o[t] = MFMA_BF16(ap, vf[t], o[t]);
  }

  // epilogue: O / l_i -> bf16 attn (n, d)
  float inv[4];
#pragma unroll
  for (int r = 0; r < 4; ++r) inv[r] = 1.0f / l_i[r];
#pragma unroll
  for (int t = 0; t < 4; ++t)
#pragma unroll
    for (int r = 0; r < 4; ++r)
      attn[(tokbase + q0 + quad * 4 + r) * DMODEL + h * DKH + t * 16 + l16] =
          (__bf16)(o[t][r] * inv[r]);
}

// ---------------- launch ------------------------------------------------------
// ws layout (bytes):
//   xb     @ 0          8388608   x as bf16 [4096][1024]
//   wqkv   @ 8388608    6291456   concat wq|wk|wv bf16 [3072][1024]
//   wob    @ 14680064   2097152   wo bf16 [1024][1024]
//   bcat   @ 16777216   12288     concat bq|bk|bv fp32 [3072]
//   qkv    @ 16789504   25165824  [4096][3072] bf16
//   vt     @ 41955328   8388608   [32*64][2048] bf16
//   attn   @ 50343936   8388608   [4096][1024] bf16    (total ~56 MB)
extern "C" void kernel_launch(void* const* d_in, const int* in_sizes, int n_in,
                              void* d_out, int out_size, void* d_ws, size_t ws_size,
                              hipStream_t stream) {
  const float* x  = (const float*)d_in[0];
  const float* wq = (const float*)d_in[1];
  const float* bq = (const float*)d_in[2];
  const float* wk = (const float*)d_in[3];
  const float* bk = (const float*)d_in[4];
  const float* wv = (const float*)d_in[5];
  const float* bv = (const float*)d_in[6];
  const float* wo = (const float*)d_in[7];
  const float* bo = (const float*)d_in[8];

  char* ws = (char*)d_ws;
  __bf16* xb    = (__bf16*)(ws + 0);
  __bf16* wqkv  = (__bf16*)(ws + 8388608);
  __bf16* wob   = (__bf16*)(ws + 14680064);
  float*  bcat  = (float*)(ws + 16777216);
  __bf16* qkv   = (__bf16*)(ws + 16789504);
  __bf16* vt    = (__bf16*)(ws + 41955328);
  __bf16* attn  = (__bf16*)(ws + 50343936);
  float*  out   = (float*)d_out;

  pack_kernel<<<1024, 256, 0, stream>>>(
      (const float4*)x, (const float4*)wq, (const float4*)wk, (const float4*)wv,
      (const float4*)wo, (const float4*)bq, (const float4*)bk, (const float4*)bv,
      (bf16x4*)xb, (bf16x4*)wqkv, (bf16x4*)wob, (float4*)bcat);

  // fused QKV projection: M=4096, N=3072, K=1024
  gemm128_bias<<<dim3(32, 24), 256, 0, stream>>>(xb, wqkv, bcat, qkv, LDQKV, 1);

  vtrans_kernel<<<dim3(32, 32), 256, 0, stream>>>(qkv, vt);

  attn_kernel<<<dim3(32, 32), 256, 0, stream>>>(qkv, vt, attn);

  // output projection: M=4096, N=1024, K=1024, fp32 out with bias bo
  gemm128_bias<<<dim3(32, 8), 256, 0, stream>>>(attn, wob, bo, out, DMODEL, 0);
}